// Round 4
// baseline (5451.674 us; speedup 1.0000x reference)
//
#include <hip/hip_runtime.h>
#include <stdint.h>

#define TN_D 1024
#define TN_F 1024
#define SENT32 0xAAAAAAAAu
#define NBLK 128   // blocks
#define CPB 8      // columns per block
#define CPW 2      // columns per wave (4 compute + 4 loader waves per block)

__device__ __forceinline__ float dot4(float4 a, float4 b) {
    return a.x * b.x + a.y * b.y + a.z * b.z + a.w * b.w;
}

// ---------------------------------------------------------------------------
// Transpose core[s][i][j] -> coreT[s][j][i], 64x64 tiles, block (16,16).
// ---------------------------------------------------------------------------
__global__ __launch_bounds__(256) void tn_transpose(const float* __restrict__ core,
                                                    float* __restrict__ coreT) {
    __shared__ float tile[64][65];
    const int s = blockIdx.z;
    const size_t base = (size_t)s * TN_D * TN_D;
    const int j0 = blockIdx.x * 64;
    const int i0 = blockIdx.y * 64;
    const int tx = threadIdx.x;
    const int ty = threadIdx.y;
#pragma unroll
    for (int r = 0; r < 4; ++r) {
        const int ii = ty + 16 * r;
        const float4 v = *(const float4*)&core[base + (size_t)(i0 + ii) * TN_D + j0 + 4 * tx];
        tile[ii][4 * tx + 0] = v.x; tile[ii][4 * tx + 1] = v.y;
        tile[ii][4 * tx + 2] = v.z; tile[ii][4 * tx + 3] = v.w;
    }
    __syncthreads();
#pragma unroll
    for (int r = 0; r < 4; ++r) {
        const int jj = ty + 16 * r;
        float4 v;
        v.x = tile[4 * tx + 0][jj]; v.y = tile[4 * tx + 1][jj];
        v.z = tile[4 * tx + 2][jj]; v.w = tile[4 * tx + 3][jj];
        *(float4*)&coreT[base + (size_t)(j0 + jj) * TN_D + i0 + 4 * tx] = v;
    }
}

// Spin until 4 dwords at vp are all != sentinel (0xAA poison; true values > 0).
__device__ __forceinline__ float4 poll4(const uint32_t* vp) {
    const unsigned long long* p = (const unsigned long long*)vp;
    unsigned long long a = __hip_atomic_load(p, __ATOMIC_RELAXED, __HIP_MEMORY_SCOPE_AGENT);
    unsigned long long b = __hip_atomic_load(p + 1, __ATOMIC_RELAXED, __HIP_MEMORY_SCOPE_AGENT);
    while ((uint32_t)a == SENT32 || (uint32_t)(a >> 32) == SENT32)
        a = __hip_atomic_load(p, __ATOMIC_RELAXED, __HIP_MEMORY_SCOPE_AGENT);
    while ((uint32_t)b == SENT32 || (uint32_t)(b >> 32) == SENT32)
        b = __hip_atomic_load(p + 1, __ATOMIC_RELAXED, __HIP_MEMORY_SCOPE_AGENT);
    return make_float4(__uint_as_float((uint32_t)a), __uint_as_float((uint32_t)(a >> 32)),
                       __uint_as_float((uint32_t)b), __uint_as_float((uint32_t)(b >> 32)));
}

// LDS epoch-counter helpers (workgroup scope on LDS => lgkmcnt-only fences).
__device__ __forceinline__ void lds_signal(int* c) {
    __hip_atomic_fetch_add(c, 1, __ATOMIC_RELEASE, __HIP_MEMORY_SCOPE_WORKGROUP);
}
__device__ __forceinline__ void lds_wait_ge(int* c, int target) {
    while (__hip_atomic_load(c, __ATOMIC_ACQUIRE, __HIP_MEMORY_SCOPE_WORKGROUP) < target) {}
}

template <bool TR>
__device__ __forceinline__ void issue_cols(const float* __restrict__ mat, int s, int j0,
                                           int l, float4 r[8]) {
    if (TR) {
        const float4* a = (const float4*)(mat + ((size_t)s * TN_D + j0) * TN_D);
        const float4* b = (const float4*)(mat + ((size_t)s * TN_D + j0 + 1) * TN_D);
        r[0] = a[l]; r[1] = a[l + 64]; r[2] = a[l + 128]; r[3] = a[l + 192];
        r[4] = b[l]; r[5] = b[l + 64]; r[6] = b[l + 128]; r[7] = b[l + 192];
    } else {
        const float* a = mat + (size_t)s * TN_D * TN_D + j0;
#pragma unroll
        for (int cc = 0; cc < 2; ++cc) {
            const float* m = a + cc;
#pragma unroll
            for (int k = 0; k < 4; ++k) {
                int i = 4 * l + 256 * k;
                r[4 * cc + k] = make_float4(m[(size_t)i * TN_D], m[(size_t)(i + 1) * TN_D],
                                            m[(size_t)(i + 2) * TN_D], m[(size_t)(i + 3) * TN_D]);
            }
        }
    }
}

// ---------------------------------------------------------------------------
// Persistent chain kernel. 128 blocks x 512 threads.
// Waves 0..3 = compute (2 columns each), waves 4..7 = loaders (2 columns each).
// NO __syncthreads in the main loop (its vmcnt(0) drain was R3's regression):
// all intra-block sync via monotonic LDS epoch counters (lgkmcnt-only).
// Loaders run up to 3 steps ahead into triple-buffered LDS. Compute waves'
// vmcnt queue holds only poll loads + the 8B publish store.
// Cross-block sync: 0xAA sentinel dataflow in vg (relaxed agent atomics).
// ---------------------------------------------------------------------------
template <bool TR>
__global__ __launch_bounds__(512, 1) void tn_chain(const int* __restrict__ x,
                                                   const float* __restrict__ mat,
                                                   const float* __restrict__ left,
                                                   const float* __restrict__ right,
                                                   float* __restrict__ vg,
                                                   float* __restrict__ out) {
    __shared__ float4 lbuf[3][CPB][TN_D / 4];  // 96 KB matrix columns
    __shared__ float4 vbuf[2][TN_D / 4];       // 8 KB vector
    __shared__ int xs[TN_F];                   // 4 KB symbol stream
    __shared__ int ctr_l, ctr_c, ctr_v, ctr_f;
    __shared__ float red[4];

    const int tid = threadIdx.x;
    const int w = tid >> 6;
    const int l = tid & 63;
    const bool is_loader = (w >= 4);

    if (tid == 0) { ctr_l = 0; ctr_c = 0; ctr_v = 0; ctr_f = 0; }
    xs[tid] = x[tid];
    xs[tid + 512] = x[tid + 512];
    __syncthreads();  // only barrier in the kernel

    if (is_loader) {
        const int lw = w - 4;
        const int j0 = blockIdx.x * CPB + 2 * lw;
        float4 cur[8], nxt[8];
        issue_cols<TR>(mat, xs[0], j0, l, cur);
        for (int u = 0; u < TN_F; ++u) {
            if (u + 1 < TN_F) issue_cols<TR>(mat, xs[u + 1], j0, l, nxt);
            // buffer u%3 free once compute finished step u-3
            if (u >= 3) lds_wait_ge(&ctr_c, 4 * (u - 2));
            const int b = u % 3;
            float4* dA = (float4*)lbuf[b][2 * lw];
            float4* dB = (float4*)lbuf[b][2 * lw + 1];
            dA[l] = cur[0]; dA[l + 64] = cur[1]; dA[l + 128] = cur[2]; dA[l + 192] = cur[3];
            dB[l] = cur[4]; dB[l + 64] = cur[5]; dB[l + 128] = cur[6]; dB[l + 192] = cur[7];
            if (l == 0) lds_signal(&ctr_l);
#pragma unroll
            for (int k = 0; k < 8; ++k) cur[k] = nxt[k];
        }
        return;
    }

    // ---------------- compute waves ----------------
    const int j0 = blockIdx.x * CPB + 2 * w;
    for (int t = 0; t < TN_F; ++t) {
        // pull v_t slice into LDS (only poll loads in this wave's vmcnt queue)
        if (t == 0) {
            vbuf[0][tid] = ((const float4*)left)[tid];
        } else {
            vbuf[t & 1][tid] = poll4((const uint32_t*)vg + (size_t)(t - 1) * TN_D + 4 * tid);
        }
        if (l == 0) lds_signal(&ctr_v);
        lds_wait_ge(&ctr_v, 4 * (t + 1));   // all vector slices in LDS
        lds_wait_ge(&ctr_l, 4 * (t + 1));   // matrix columns for step t staged

        const float4* vv = (const float4*)vbuf[t & 1];
        const float4* mA = (const float4*)lbuf[t % 3][2 * w];
        const float4* mB = (const float4*)lbuf[t % 3][2 * w + 1];
        float a0 = 0.f, a1 = 0.f;
#pragma unroll
        for (int k = 0; k < 4; ++k) {
            const float4 v = vv[l + 64 * k];
            a0 += dot4(v, mA[l + 64 * k]);
            a1 += dot4(v, mB[l + 64 * k]);
        }
#pragma unroll
        for (int off = 32; off; off >>= 1) {
            a0 += __shfl_down(a0, off, 64);
            a1 += __shfl_down(a1, off, 64);
        }
        if (l == 0) {
            const unsigned long long pk =
                (unsigned long long)__float_as_uint(a0) |
                ((unsigned long long)__float_as_uint(a1) << 32);
            __hip_atomic_store((unsigned long long*)(vg + (size_t)t * TN_D + j0), pk,
                               __ATOMIC_RELAXED, __HIP_MEMORY_SCOPE_AGENT);
            lds_signal(&ctr_c);  // buffer t%3 consumed by this wave
        }
    }

    // ---------------- final dot with right boundary: block 0 ----------------
    if (blockIdx.x == 0) {
        float4 v = poll4((const uint32_t*)vg + (size_t)(TN_F - 1) * TN_D + 4 * tid);
        float p = dot4(v, ((const float4*)right)[tid]);
#pragma unroll
        for (int off = 32; off; off >>= 1) p += __shfl_down(p, off, 64);
        if (l == 0) { red[w] = p; lds_signal(&ctr_f); }
        if (w == 0) {
            lds_wait_ge(&ctr_f, 4);
            if (l == 0) out[0] = red[0] + red[1] + red[2] + red[3];
        }
    }
}

extern "C" void kernel_launch(void* const* d_in, const int* in_sizes, int n_in,
                              void* d_out, int out_size, void* d_ws, size_t ws_size,
                              hipStream_t stream) {
    const int* x = (const int*)d_in[0];
    const float* core = (const float*)d_in[1];
    const float* left = (const float*)d_in[2];
    const float* right = (const float*)d_in[3];
    float* out = (float*)d_out;

    const int nsym = in_sizes[1] / (TN_D * TN_D);
    const size_t coreBytes = (size_t)in_sizes[1] * sizeof(float);
    const size_t vbufBytes = (size_t)TN_F * TN_D * sizeof(float);

    if (ws_size >= coreBytes + vbufBytes) {
        float* coreT = (float*)d_ws;
        float* vg = (float*)((char*)d_ws + coreBytes);
        hipMemsetAsync(vg, 0xAA, vbufBytes, stream);
        tn_transpose<<<dim3(16, 16, nsym), dim3(16, 16), 0, stream>>>(core, coreT);
        tn_chain<true><<<NBLK, 512, 0, stream>>>(x, coreT, left, right, vg, out);
    } else {
        float* vg = (float*)d_ws;
        hipMemsetAsync(vg, 0xAA, vbufBytes, stream);
        tn_chain<false><<<NBLK, 512, 0, stream>>>(x, core, left, right, vg, out);
    }
}

// Round 5
// 4511.105 us; speedup vs baseline: 1.2085x; 1.2085x over previous
//
#include <hip/hip_runtime.h>
#include <stdint.h>

#define TN_D 1024
#define TN_F 1024
#define SENT32 0xAAAAAAAAu

typedef _Float16 half4_t __attribute__((ext_vector_type(4)));

__device__ __forceinline__ float dot4(float4 a, float4 b) {
    return a.x * b.x + a.y * b.y + a.z * b.z + a.w * b.w;
}
__device__ __forceinline__ float dot4h(float4 v, half4_t m) {
    return v.x * (float)m.x + v.y * (float)m.y + v.z * (float)m.z + v.w * (float)m.w;
}

// ---------------------------------------------------------------------------
// Transpose + convert: core[s][i][j] f32 -> coreT[s][j][i] f16.
// ---------------------------------------------------------------------------
__global__ __launch_bounds__(256) void tn_transpose(const float* __restrict__ core,
                                                    _Float16* __restrict__ coreT) {
    __shared__ float tile[64][65];
    const int s = blockIdx.z;
    const size_t base = (size_t)s * TN_D * TN_D;
    const int j0 = blockIdx.x * 64;
    const int i0 = blockIdx.y * 64;
    const int tx = threadIdx.x;
    const int ty = threadIdx.y;
#pragma unroll
    for (int r = 0; r < 4; ++r) {
        const int ii = ty + 16 * r;
        const float4 v = *(const float4*)&core[base + (size_t)(i0 + ii) * TN_D + j0 + 4 * tx];
        tile[ii][4 * tx + 0] = v.x; tile[ii][4 * tx + 1] = v.y;
        tile[ii][4 * tx + 2] = v.z; tile[ii][4 * tx + 3] = v.w;
    }
    __syncthreads();
#pragma unroll
    for (int r = 0; r < 4; ++r) {
        const int jj = ty + 16 * r;
        half4_t h;
        h.x = (_Float16)tile[4 * tx + 0][jj];
        h.y = (_Float16)tile[4 * tx + 1][jj];
        h.z = (_Float16)tile[4 * tx + 2][jj];
        h.w = (_Float16)tile[4 * tx + 3][jj];
        *(half4_t*)&coreT[base + (size_t)(j0 + jj) * TN_D + i0 + 4 * tx] = h;
    }
}

// Spin until 4 dwords at vp are all != sentinel (0xAA poison; true values > 0).
__device__ __forceinline__ float4 poll4(const uint32_t* vp) {
    const unsigned long long* p = (const unsigned long long*)vp;
    unsigned long long a = __hip_atomic_load(p, __ATOMIC_RELAXED, __HIP_MEMORY_SCOPE_AGENT);
    unsigned long long b = __hip_atomic_load(p + 1, __ATOMIC_RELAXED, __HIP_MEMORY_SCOPE_AGENT);
    while ((uint32_t)a == SENT32 || (uint32_t)(a >> 32) == SENT32)
        a = __hip_atomic_load(p, __ATOMIC_RELAXED, __HIP_MEMORY_SCOPE_AGENT);
    while ((uint32_t)b == SENT32 || (uint32_t)(b >> 32) == SENT32)
        b = __hip_atomic_load(p + 1, __ATOMIC_RELAXED, __HIP_MEMORY_SCOPE_AGENT);
    return make_float4(__uint_as_float((uint32_t)a), __uint_as_float((uint32_t)(a >> 32)),
                       __uint_as_float((uint32_t)b), __uint_as_float((uint32_t)(b >> 32)));
}

// ---------------------------------------------------------------------------
// Persistent chain, f16 matrix. 256 blocks x 256 threads; wave w owns column
// j = 4*blk + w. Per-step order: poll(t-1) -> barrier -> issue cols(t+1) ->
// compute(t) -> publish(t). The poll's vmcnt(0) therefore sees only poll
// loads (column loads were issued a full step earlier); the barrier drains
// only stale loads. Manual 2x unroll (register sets A/B) avoids copy-forced
// early waits. Cross-block sync via 0xAA sentinel dataflow (relaxed agent).
// ---------------------------------------------------------------------------
__global__ __launch_bounds__(256, 1) void tn_chain_f16(const int* __restrict__ x,
                                                       const _Float16* __restrict__ mat,
                                                       const float* __restrict__ left,
                                                       const float* __restrict__ right,
                                                       float* __restrict__ vg,
                                                       float* __restrict__ out) {
    __shared__ float4 lv[2][TN_D / 4];  // 8 KB double-buffered v
    __shared__ int xs[TN_F];            // 4 KB symbol stream
    __shared__ float red[4];

    const int tid = threadIdx.x;
    const int w = tid >> 6;
    const int l = tid & 63;
    const int j = blockIdx.x * 4 + w;

    ((int4*)xs)[tid] = ((const int4*)x)[tid];
    __syncthreads();

    half4_t A0, A1, A2, A3, B0, B1, B2, B3;
    {
        const half4_t* cp = (const half4_t*)(mat + ((size_t)xs[0] * TN_D + j) * TN_D);
        A0 = cp[l]; A1 = cp[l + 64]; A2 = cp[l + 128]; A3 = cp[l + 192];
    }

    for (int t = 0; t < TN_F; t += 2) {
        // symbols for upcoming prefetches (LDS reads, off the vmem path)
        const int s1 = xs[(t + 1 < TN_F) ? t + 1 : TN_F - 1];
        const int s2 = xs[(t + 2 < TN_F) ? t + 2 : TN_F - 1];

        // ================= even step t: compute with A =================
        if (t == 0) {
            lv[0][tid] = ((const float4*)left)[tid];
        } else {
            lv[0][tid] = poll4((const uint32_t*)vg + (size_t)(t - 1) * TN_D + 4 * tid);
        }
        __syncthreads();
        {   // prefetch cols for t+1 into B (issued AFTER the barrier)
            const half4_t* cp = (const half4_t*)(mat + ((size_t)s1 * TN_D + j) * TN_D);
            B0 = cp[l]; B1 = cp[l + 64]; B2 = cp[l + 128]; B3 = cp[l + 192];
        }
        {
            const float4* vv = lv[0];
            float acc = dot4h(vv[l], A0) + dot4h(vv[l + 64], A1) +
                        dot4h(vv[l + 128], A2) + dot4h(vv[l + 192], A3);
#pragma unroll
            for (int off = 32; off; off >>= 1) acc += __shfl_down(acc, off, 64);
            if (l == 0)
                __hip_atomic_store((uint32_t*)vg + (size_t)t * TN_D + j,
                                   __float_as_uint(acc), __ATOMIC_RELAXED,
                                   __HIP_MEMORY_SCOPE_AGENT);
        }

        // ================= odd step t+1: compute with B =================
        lv[1][tid] = poll4((const uint32_t*)vg + (size_t)t * TN_D + 4 * tid);
        __syncthreads();
        {   // prefetch cols for t+2 into A
            const half4_t* cp = (const half4_t*)(mat + ((size_t)s2 * TN_D + j) * TN_D);
            A0 = cp[l]; A1 = cp[l + 64]; A2 = cp[l + 128]; A3 = cp[l + 192];
        }
        {
            const float4* vv = lv[1];
            float acc = dot4h(vv[l], B0) + dot4h(vv[l + 64], B1) +
                        dot4h(vv[l + 128], B2) + dot4h(vv[l + 192], B3);
#pragma unroll
            for (int off = 32; off; off >>= 1) acc += __shfl_down(acc, off, 64);
            if (l == 0)
                __hip_atomic_store((uint32_t*)vg + (size_t)(t + 1) * TN_D + j,
                                   __float_as_uint(acc), __ATOMIC_RELAXED,
                                   __HIP_MEMORY_SCOPE_AGENT);
        }
    }

    // ---- final dot with right boundary: block 0 ----
    if (blockIdx.x == 0) {
        float4 v = poll4((const uint32_t*)vg + (size_t)(TN_F - 1) * TN_D + 4 * tid);
        float p = dot4(v, ((const float4*)right)[tid]);
#pragma unroll
        for (int off = 32; off; off >>= 1) p += __shfl_down(p, off, 64);
        if (l == 0) red[w] = p;
        __syncthreads();
        if (tid == 0) out[0] = red[0] + red[1] + red[2] + red[3];
    }
}

// ---------------------------------------------------------------------------
// Fallback (tiny workspace): R2-structure fp32, no transpose. Rarely used.
// ---------------------------------------------------------------------------
__global__ __launch_bounds__(256, 1) void tn_chain_f32(const int* __restrict__ x,
                                                       const float* __restrict__ mat,
                                                       const float* __restrict__ left,
                                                       const float* __restrict__ right,
                                                       float* __restrict__ vg,
                                                       float* __restrict__ out) {
    __shared__ float4 lv[2][TN_D / 4];
    __shared__ float red[4];
    const int tid = threadIdx.x;
    const int w = tid >> 6;
    const int l = tid & 63;
    const int j = blockIdx.x * 4 + w;

    for (int t = 0; t < TN_F; ++t) {
        if (t == 0) lv[0][tid] = ((const float4*)left)[tid];
        else lv[t & 1][tid] = poll4((const uint32_t*)vg + (size_t)(t - 1) * TN_D + 4 * tid);
        __syncthreads();
        const float* mp = mat + (size_t)x[t] * TN_D * TN_D + j;
        const float4* vv = lv[t & 1];
        float acc = 0.f;
#pragma unroll
        for (int k = 0; k < 4; ++k) {
            const int i = 4 * l + 256 * k;
            const float4 v = vv[l + 64 * k];
            acc += v.x * mp[(size_t)i * TN_D] + v.y * mp[(size_t)(i + 1) * TN_D] +
                   v.z * mp[(size_t)(i + 2) * TN_D] + v.w * mp[(size_t)(i + 3) * TN_D];
        }
#pragma unroll
        for (int off = 32; off; off >>= 1) acc += __shfl_down(acc, off, 64);
        if (l == 0)
            __hip_atomic_store((uint32_t*)vg + (size_t)t * TN_D + j, __float_as_uint(acc),
                               __ATOMIC_RELAXED, __HIP_MEMORY_SCOPE_AGENT);
    }
    if (blockIdx.x == 0) {
        float4 v = poll4((const uint32_t*)vg + (size_t)(TN_F - 1) * TN_D + 4 * tid);
        float p = dot4(v, ((const float4*)right)[tid]);
#pragma unroll
        for (int off = 32; off; off >>= 1) p += __shfl_down(p, off, 64);
        if (l == 0) red[w] = p;
        __syncthreads();
        if (tid == 0) out[0] = red[0] + red[1] + red[2] + red[3];
    }
}

extern "C" void kernel_launch(void* const* d_in, const int* in_sizes, int n_in,
                              void* d_out, int out_size, void* d_ws, size_t ws_size,
                              hipStream_t stream) {
    const int* x = (const int*)d_in[0];
    const float* core = (const float*)d_in[1];
    const float* left = (const float*)d_in[2];
    const float* right = (const float*)d_in[3];
    float* out = (float*)d_out;

    const int nsym = in_sizes[1] / (TN_D * TN_D);
    const size_t coreTBytes = (size_t)in_sizes[1] * sizeof(_Float16);  // 64 MB
    const size_t vbufBytes = (size_t)TN_F * TN_D * sizeof(float);      // 4 MB

    if (ws_size >= coreTBytes + vbufBytes) {
        _Float16* coreT = (_Float16*)d_ws;
        float* vg = (float*)((char*)d_ws + coreTBytes);
        hipMemsetAsync(vg, 0xAA, vbufBytes, stream);
        tn_transpose<<<dim3(16, 16, nsym), dim3(16, 16), 0, stream>>>(core, coreT);
        tn_chain_f16<<<256, 256, 0, stream>>>(x, coreT, left, right, vg, out);
    } else {
        float* vg = (float*)d_ws;
        hipMemsetAsync(vg, 0xAA, vbufBytes, stream);
        tn_chain_f32<<<256, 256, 0, stream>>>(x, core, left, right, vg, out);
    }
}

// Round 6
// 1832.525 us; speedup vs baseline: 2.9750x; 2.4617x over previous
//
#include <hip/hip_runtime.h>
#include <stdint.h>

#define TN_D 1024
#define TN_F 1024
#define SENT32 0xAAAAAAAAu
#define NBLK 64
#define CPB 16  // columns per block (1 per wave, 16 waves)

typedef _Float16 half8_t __attribute__((ext_vector_type(8)));

// ---------------------------------------------------------------------------
// Transpose + convert: core[s][i][j] f32 -> coreT[s][j][i] f16.
// ---------------------------------------------------------------------------
__global__ __launch_bounds__(256) void tn_transpose(const float* __restrict__ core,
                                                    _Float16* __restrict__ coreT) {
    __shared__ float tile[64][65];
    const int s = blockIdx.z;
    const size_t base = (size_t)s * TN_D * TN_D;
    const int j0 = blockIdx.x * 64;
    const int i0 = blockIdx.y * 64;
    const int tx = threadIdx.x;
    const int ty = threadIdx.y;
#pragma unroll
    for (int r = 0; r < 4; ++r) {
        const int ii = ty + 16 * r;
        const float4 v = *(const float4*)&core[base + (size_t)(i0 + ii) * TN_D + j0 + 4 * tx];
        tile[ii][4 * tx + 0] = v.x; tile[ii][4 * tx + 1] = v.y;
        tile[ii][4 * tx + 2] = v.z; tile[ii][4 * tx + 3] = v.w;
    }
    __syncthreads();
#pragma unroll
    for (int r = 0; r < 4; ++r) {
        const int jj = ty + 16 * r;
        _Float16 h4[4];
        h4[0] = (_Float16)tile[4 * tx + 0][jj];
        h4[1] = (_Float16)tile[4 * tx + 1][jj];
        h4[2] = (_Float16)tile[4 * tx + 2][jj];
        h4[3] = (_Float16)tile[4 * tx + 3][jj];
        *(uint64_t*)&coreT[base + (size_t)(j0 + jj) * TN_D + i0 + 4 * tx] = *(uint64_t*)h4;
    }
}

// Spin until dword at p != sentinel (0xAA poison; true values are positive).
__device__ __forceinline__ float poll1(const uint32_t* p) {
    uint32_t u = __hip_atomic_load(p, __ATOMIC_RELAXED, __HIP_MEMORY_SCOPE_AGENT);
    while (u == SENT32)
        u = __hip_atomic_load(p, __ATOMIC_RELAXED, __HIP_MEMORY_SCOPE_AGENT);
    return __uint_as_float(u);
}

__device__ __forceinline__ float dot8h(float4 a, float4 b, half8_t h) {
    return a.x * (float)h[0] + a.y * (float)h[1] + a.z * (float)h[2] + a.w * (float)h[3] +
           b.x * (float)h[4] + b.y * (float)h[5] + b.z * (float)h[6] + b.w * (float)h[7];
}

// ---------------------------------------------------------------------------
// Persistent chain, f16 matrix. 64 blocks x 1024 threads (16 waves); wave w
// owns column j = 16*blk + w. Per step: each thread polls ONE dword of the
// previous v-row (agent atomics), writes it to LDS; one barrier; each wave
// dots its register-prefetched f16 column vs LDS v; lane0 deposits the
// result in sentinel-guarded volatile LDS (pure ds ops, no fences); wave 0
// gathers all 16 and issues ONE coalesced 64B agent-store per block.
// The per-step __syncthreads orders the redv read/poison against next-step
// redv writes (waves cannot pass the barrier until wave0 finished reading).
// ---------------------------------------------------------------------------
__global__ __launch_bounds__(1024, 1) void tn_chain_f16(const int* __restrict__ x,
                                                        const _Float16* __restrict__ mat,
                                                        const float* __restrict__ left,
                                                        const float* __restrict__ right,
                                                        float* __restrict__ vg,
                                                        float* __restrict__ out) {
    __shared__ float lv[2][TN_D];           // 8 KB double-buffered v
    __shared__ int xs[TN_F];                // 4 KB symbol stream
    volatile __shared__ uint32_t redv[CPB]; // per-wave results, sentinel-guarded
    __shared__ float red2[CPB];

    const int tid = threadIdx.x;
    const int w = tid >> 6;
    const int l = tid & 63;
    const int j = blockIdx.x * CPB + w;

    xs[tid] = x[tid];
    if (tid < CPB) redv[tid] = SENT32;
    __syncthreads();

    half8_t A0, A1, B0, B1;
    {
        const half8_t* cp = (const half8_t*)(mat + ((size_t)xs[0] * TN_D + j) * TN_D);
        A0 = cp[l]; A1 = cp[l + 64];
    }

    for (int t = 0; t < TN_F; t += 2) {
        const int s1 = xs[(t + 1 < TN_F) ? t + 1 : TN_F - 1];
        const int s2 = xs[(t + 2 < TN_F) ? t + 2 : TN_F - 1];

        // ================= even step t (registers A) =================
        if (t == 0) lv[0][tid] = left[tid];
        else        lv[0][tid] = poll1((const uint32_t*)vg + (size_t)(t - 1) * TN_D + tid);
        __syncthreads();
        {   // prefetch col for t+1 (drained only at the NEXT barrier, a step away)
            const half8_t* cp = (const half8_t*)(mat + ((size_t)s1 * TN_D + j) * TN_D);
            B0 = cp[l]; B1 = cp[l + 64];
        }
        {
            const float4* vv = (const float4*)lv[0];
            float acc = dot8h(vv[2 * l], vv[2 * l + 1], A0) +
                        dot8h(vv[2 * l + 128], vv[2 * l + 129], A1);
#pragma unroll
            for (int off = 32; off; off >>= 1) acc += __shfl_down(acc, off, 64);
            if (l == 0) {
                __asm__ volatile("" ::: "memory");
                redv[w] = __float_as_uint(acc);
            }
            if (w == 0 && l < CPB) {
                uint32_t u = redv[l];
                while (u == SENT32) u = redv[l];
                redv[l] = SENT32;  // re-poison BEFORE the store becomes visible
                __asm__ volatile("" ::: "memory");
                __hip_atomic_store((uint32_t*)vg + (size_t)t * TN_D + blockIdx.x * CPB + l,
                                   u, __ATOMIC_RELAXED, __HIP_MEMORY_SCOPE_AGENT);
            }
        }

        // ================= odd step t+1 (registers B) =================
        lv[1][tid] = poll1((const uint32_t*)vg + (size_t)t * TN_D + tid);
        __syncthreads();
        {   // prefetch col for t+2
            const half8_t* cp = (const half8_t*)(mat + ((size_t)s2 * TN_D + j) * TN_D);
            A0 = cp[l]; A1 = cp[l + 64];
        }
        {
            const float4* vv = (const float4*)lv[1];
            float acc = dot8h(vv[2 * l], vv[2 * l + 1], B0) +
                        dot8h(vv[2 * l + 128], vv[2 * l + 129], B1);
#pragma unroll
            for (int off = 32; off; off >>= 1) acc += __shfl_down(acc, off, 64);
            if (l == 0) {
                __asm__ volatile("" ::: "memory");
                redv[w] = __float_as_uint(acc);
            }
            if (w == 0 && l < CPB) {
                uint32_t u = redv[l];
                while (u == SENT32) u = redv[l];
                redv[l] = SENT32;
                __asm__ volatile("" ::: "memory");
                __hip_atomic_store((uint32_t*)vg + (size_t)(t + 1) * TN_D + blockIdx.x * CPB + l,
                                   u, __ATOMIC_RELAXED, __HIP_MEMORY_SCOPE_AGENT);
            }
        }
    }

    // ---- final dot with right boundary: block 0 ----
    if (blockIdx.x == 0) {
        float v = poll1((const uint32_t*)vg + (size_t)(TN_F - 1) * TN_D + tid);
        float p = v * right[tid];
#pragma unroll
        for (int off = 32; off; off >>= 1) p += __shfl_down(p, off, 64);
        if (l == 0) red2[w] = p;
        __syncthreads();
        if (tid == 0) {
            float s = 0.f;
#pragma unroll
            for (int k = 0; k < CPB; ++k) s += red2[k];
            out[0] = s;
        }
    }
}

// ---------------------------------------------------------------------------
// Fallback (tiny workspace): R2-structure fp32, no transpose.
// ---------------------------------------------------------------------------
__device__ __forceinline__ float4 poll4(const uint32_t* vp) {
    const unsigned long long* p = (const unsigned long long*)vp;
    unsigned long long a = __hip_atomic_load(p, __ATOMIC_RELAXED, __HIP_MEMORY_SCOPE_AGENT);
    unsigned long long b = __hip_atomic_load(p + 1, __ATOMIC_RELAXED, __HIP_MEMORY_SCOPE_AGENT);
    while ((uint32_t)a == SENT32 || (uint32_t)(a >> 32) == SENT32)
        a = __hip_atomic_load(p, __ATOMIC_RELAXED, __HIP_MEMORY_SCOPE_AGENT);
    while ((uint32_t)b == SENT32 || (uint32_t)(b >> 32) == SENT32)
        b = __hip_atomic_load(p + 1, __ATOMIC_RELAXED, __HIP_MEMORY_SCOPE_AGENT);
    return make_float4(__uint_as_float((uint32_t)a), __uint_as_float((uint32_t)(a >> 32)),
                       __uint_as_float((uint32_t)b), __uint_as_float((uint32_t)(b >> 32)));
}

__global__ __launch_bounds__(256, 1) void tn_chain_f32(const int* __restrict__ x,
                                                       const float* __restrict__ mat,
                                                       const float* __restrict__ left,
                                                       const float* __restrict__ right,
                                                       float* __restrict__ vg,
                                                       float* __restrict__ out) {
    __shared__ float4 lv[2][TN_D / 4];
    __shared__ float red[4];
    const int tid = threadIdx.x;
    const int w = tid >> 6;
    const int l = tid & 63;
    const int j = blockIdx.x * 4 + w;

    for (int t = 0; t < TN_F; ++t) {
        if (t == 0) lv[0][tid] = ((const float4*)left)[tid];
        else lv[t & 1][tid] = poll4((const uint32_t*)vg + (size_t)(t - 1) * TN_D + 4 * tid);
        __syncthreads();
        const float* mp = mat + (size_t)x[t] * TN_D * TN_D + j;
        const float4* vv = lv[t & 1];
        float acc = 0.f;
#pragma unroll
        for (int k = 0; k < 4; ++k) {
            const int i = 4 * l + 256 * k;
            const float4 v = vv[l + 64 * k];
            acc += v.x * mp[(size_t)i * TN_D] + v.y * mp[(size_t)(i + 1) * TN_D] +
                   v.z * mp[(size_t)(i + 2) * TN_D] + v.w * mp[(size_t)(i + 3) * TN_D];
        }
#pragma unroll
        for (int off = 32; off; off >>= 1) acc += __shfl_down(acc, off, 64);
        if (l == 0)
            __hip_atomic_store((uint32_t*)vg + (size_t)t * TN_D + j, __float_as_uint(acc),
                               __ATOMIC_RELAXED, __HIP_MEMORY_SCOPE_AGENT);
    }
    if (blockIdx.x == 0) {
        float4 v = poll4((const uint32_t*)vg + (size_t)(TN_F - 1) * TN_D + 4 * tid);
        const float4 r4 = ((const float4*)right)[tid];
        float p = v.x * r4.x + v.y * r4.y + v.z * r4.z + v.w * r4.w;
#pragma unroll
        for (int off = 32; off; off >>= 1) p += __shfl_down(p, off, 64);
        if (l == 0) red[w] = p;
        __syncthreads();
        if (tid == 0) out[0] = red[0] + red[1] + red[2] + red[3];
    }
}

extern "C" void kernel_launch(void* const* d_in, const int* in_sizes, int n_in,
                              void* d_out, int out_size, void* d_ws, size_t ws_size,
                              hipStream_t stream) {
    const int* x = (const int*)d_in[0];
    const float* core = (const float*)d_in[1];
    const float* left = (const float*)d_in[2];
    const float* right = (const float*)d_in[3];
    float* out = (float*)d_out;

    const int nsym = in_sizes[1] / (TN_D * TN_D);
    const size_t coreTBytes = (size_t)in_sizes[1] * sizeof(_Float16);  // 64 MB
    const size_t vbufBytes = (size_t)TN_F * TN_D * sizeof(float);      // 4 MB

    if (ws_size >= coreTBytes + vbufBytes) {
        _Float16* coreT = (_Float16*)d_ws;
        float* vg = (float*)((char*)d_ws + coreTBytes);
        hipMemsetAsync(vg, 0xAA, vbufBytes, stream);
        tn_transpose<<<dim3(16, 16, nsym), dim3(16, 16), 0, stream>>>(core, coreT);
        tn_chain_f16<<<NBLK, 1024, 0, stream>>>(x, coreT, left, right, vg, out);
    } else {
        float* vg = (float*)d_ws;
        hipMemsetAsync(vg, 0xAA, vbufBytes, stream);
        tn_chain_f32<<<256, 256, 0, stream>>>(x, core, left, right, vg, out);
    }
}